// Round 16
// baseline (163.051 us; speedup 1.0000x reference)
//
#include <hip/hip_runtime.h>

// Navier-Stokes physics-informed loss (f32 in, scalar f32 out).
// x,y: (64,3,512,512). Interior: b in [1,62], i,j in [1,510].
// r0 = |dudx + dvdy| ; r1 = |dudt + u*dudx + v*dudy + dpdx - MU*lap u| ;
// r2 = |dvdt + u*dvdx + v*dvdy + dpdy - MU*lap v| ; dudt=(u[b+1]-u[b-1])*32
//
// R16: 2-D wave tiling. Wave = 8 i-rows x 8 f4-cols (32 j). i+-1 = lane+-8
// shfl (in-register; no LDS, NO barriers). j+-1 = lane+-1 shfl. b+-1 from
// carried um/uc/un chain (each u,v loaded once; depth-1 prefetch of b+2,
// R12-proven). Edge rows (il 0/7) + j-group boundary scalars (jl 0/7)
// loaded same-iter. Requested ~0.52 GB (vs R14 0.59 with 31 barriers).
// VGPR gate: must stay <=128 (4 waves/SIMD, m69 cliff). Grid 1024 =
// 8 XCD groups x (16 i-tiles x 8 j-tiles); each XCD owns one (b-chunk,
// j-half): per-plane set ~3MB fits its L2.

constexpr int Wd   = 512;
constexpr int CSTR = 512 * 512;
constexpr int BSTR = 3 * 512 * 512;

__device__ __forceinline__ float4 ld4(const float* p) {
    return *reinterpret_cast<const float4*>(p);
}
__device__ __forceinline__ float4 scale4(float4 a, float s) {
    return make_float4(a.x * s, a.y * s, a.z * s, a.w * s);
}
__device__ __forceinline__ float4 shup8(float4 a) {
    return make_float4(__shfl_up(a.x, 8), __shfl_up(a.y, 8),
                       __shfl_up(a.z, 8), __shfl_up(a.w, 8));
}
__device__ __forceinline__ float4 shdn8(float4 a) {
    return make_float4(__shfl_down(a.x, 8), __shfl_down(a.y, 8),
                       __shfl_down(a.z, 8), __shfl_down(a.w, 8));
}

// One tensor, one plane. um,uc,un / vm,vc,vn: scaled b-chain. pc: raw p row.
// eu,ev (scaled), ep (raw): edge neighbor row (i-1 for il==0, i+1 for il==7).
// uL..pR: j-boundary scalars (valid on jl==0 / jl==7 lanes).
__device__ __forceinline__ void resid(
    int il, int jl,
    float4 um, float4 uc, float4 un,
    float4 vm, float4 vc, float4 vn,
    float4 pc,
    float4 eu, float4 ev, float4 ep,
    float uL, float vL, float pL,
    float uR, float vR, float pR,
    float sdx,
    float r0[4], float r1[4], float r2[4])
{
    // i+-1 via cross-row shfl (+-8 lanes); edge rows override.
    const float4 ucm = shup8(uc), ucp = shdn8(uc);
    const float4 vcm = shup8(vc), vcp = shdn8(vc);
    const float4 pcm = shup8(pc), pcp = shdn8(pc);
    const bool top = (il == 0), bot = (il == 7);
    const float4 uxm = top ? eu : ucm;
    const float4 uxp = bot ? eu : ucp;
    const float4 vxm = top ? ev : vcm;
    const float4 vxp = bot ? ev : vcp;
    const float4 pxm = top ? ep : pcm;
    const float4 pxp = bot ? ep : pcp;

    // j+-1 via lane+-1 shfl; group-boundary lanes use loaded scalars.
    float u_l = __shfl_up(uc.w, 1);
    float v_l = __shfl_up(vc.w, 1);
    float p_l = __shfl_up(pc.w, 1);
    float u_r = __shfl_down(uc.x, 1);
    float v_r = __shfl_down(vc.x, 1);
    float p_r = __shfl_down(pc.x, 1);
    if (jl == 0) { u_l = uL; v_l = vL; p_l = pL; }
    if (jl == 7) { u_r = uR; v_r = vR; p_r = pR; }

    const float ucA[4] = {uc.x, uc.y, uc.z, uc.w};
    const float vcA[4] = {vc.x, vc.y, vc.z, vc.w};
    const float umA[4] = {um.x, um.y, um.z, um.w};
    const float vmA[4] = {vm.x, vm.y, vm.z, vm.w};
    const float unA[4] = {un.x, un.y, un.z, un.w};
    const float vnA[4] = {vn.x, vn.y, vn.z, vn.w};
    const float ul[4]  = {u_l, uc.x, uc.y, uc.z};
    const float ur[4]  = {uc.y, uc.z, uc.w, u_r};
    const float vl[4]  = {v_l, vc.x, vc.y, vc.z};
    const float vr[4]  = {vc.y, vc.z, vc.w, v_r};
    const float pl[4]  = {p_l, pc.x, pc.y, pc.z};
    const float pr[4]  = {pc.y, pc.z, pc.w, p_r};
    const float uxpA[4] = {uxp.x, uxp.y, uxp.z, uxp.w};
    const float uxmA[4] = {uxm.x, uxm.y, uxm.z, uxm.w};
    const float vxpA[4] = {vxp.x, vxp.y, vxp.z, vxp.w};
    const float vxmA[4] = {vxm.x, vxm.y, vxm.z, vxm.w};
    const float pxpA[4] = {pxp.x, pxp.y, pxp.z, pxp.w};
    const float pxmA[4] = {pxm.x, pxm.y, pxm.z, pxm.w};

    #pragma unroll
    for (int k = 0; k < 4; ++k) {
        const float dudx = (uxpA[k] - uxmA[k]) * 127.5f;   // scaled inputs
        const float dvdx = (vxpA[k] - vxmA[k]) * 127.5f;
        const float dpdx = (pxpA[k] - pxmA[k]) * sdx;      // raw p
        const float dudy = (ur[k] - ul[k]) * 127.5f;
        const float dvdy = (vr[k] - vl[k]) * 127.5f;
        const float dpdy = (pr[k] - pl[k]) * sdx;
        const float lapu = (uxpA[k] + uxmA[k] + ur[k] + ul[k]) * 0.65025f
                         - 2.601f * ucA[k];
        const float lapv = (vxpA[k] + vxmA[k] + vr[k] + vl[k]) * 0.65025f
                         - 2.601f * vcA[k];
        r0[k] = fabsf(dudx + dvdy);
        r1[k] = fabsf((unA[k] - umA[k]) * 32.0f + ucA[k] * dudx + vcA[k] * dudy
                      + dpdx - lapu);
        r2[k] = fabsf((vnA[k] - vmA[k]) * 32.0f + ucA[k] * dvdx + vcA[k] * dvdy
                      + dpdy - lapv);
    }
}

__global__ __launch_bounds__(256)
void ns_loss_kernel(const float* __restrict__ X, const float* __restrict__ Y,
                    const float* __restrict__ stdp, double* __restrict__ acc)
{
    const float s   = *stdp;
    const float sdx = s * 127.5f;

    // 1024 blocks = 8 XCD groups x 128. Group -> (b-chunk z, j-half jh);
    // within group: 16 i-tiles (minor) x 8 j-tiles.
    const int orig = blockIdx.x;
    const int grp  = orig & 7;
    const int idx  = orig >> 3;          // 0..127
    const int z    = grp >> 1;           // 0..3
    const int jh   = grp & 1;            // 0..1
    const int bi   = idx & 15;           // i-tile 0..15
    const int bj   = jh * 8 + (idx >> 4);// j-tile 0..15

    const int tid  = threadIdx.x;
    const int w    = tid >> 6;           // wave 0..3 (stacked in i)
    const int lane = tid & 63;
    const int il   = lane >> 3;          // row in wave 0..7
    const int jl   = lane & 7;           // f4-col in wave 0..7

    const int i_nom = 1 + bi * 32 + w * 8 + il;   // 1..512
    const int i     = min(i_nom, 511);
    const bool vrow = (i_nom <= 510);
    const int j0    = bj * 32 + jl * 4;           // 0..508

    const int bs     = (z < 2) ? (1 + 16 * z) : (33 + 15 * (z - 2)); // 1,17,33,48
    const int nsteps = (z < 2) ? 16 : 15;

    int c = bs * BSTR + i * Wd + j0;
    const int eoff   = (il == 0) ? -Wd : ((i < 511) ? Wd : 0);
    const bool isedge = (il == 0) || (il == 7);
    const int offL = (j0 == 0) ? 0 : -1;           // clamped; masked at k=0
    const int offR = (j0 == 508) ? 3 : 4;          // clamped; masked at k=3

    // prologue: b-chains (scaled)
    float4 xum = scale4(ld4(X + c - BSTR), s);
    float4 xuc = scale4(ld4(X + c), s);
    float4 xun = scale4(ld4(X + c + BSTR), s);
    float4 xvm = scale4(ld4(X + c - BSTR + CSTR), s);
    float4 xvc = scale4(ld4(X + c + CSTR), s);
    float4 xvn = scale4(ld4(X + c + BSTR + CSTR), s);
    float4 yum = scale4(ld4(Y + c - BSTR), s);
    float4 yuc = scale4(ld4(Y + c), s);
    float4 yun = scale4(ld4(Y + c + BSTR), s);
    float4 yvm = scale4(ld4(Y + c - BSTR + CSTR), s);
    float4 yvc = scale4(ld4(Y + c + CSTR), s);
    float4 yvn = scale4(ld4(Y + c + BSTR + CSTR), s);

    float s0 = 0.0f, s1 = 0.0f, s2 = 0.0f;

    for (int it = 0; it < nsteps; ++it) {
        const int pf = (it + 1 < nsteps) ? 2 * BSTR : BSTR;  // clamp last iter

        // same-plane p centers + chain prefetch (b+2)
        const float4 xpc  = ld4(X + c + 2 * CSTR);
        const float4 ypc  = ld4(Y + c + 2 * CSTR);
        const float4 xun2 = scale4(ld4(X + c + pf), s);
        const float4 xvn2 = scale4(ld4(X + c + pf + CSTR), s);
        const float4 yun2 = scale4(ld4(Y + c + pf), s);
        const float4 yvn2 = scale4(ld4(Y + c + pf + CSTR), s);

        // edge neighbor rows at plane b (il==0: i-1 ; il==7: i+1)
        float4 xeu = make_float4(0, 0, 0, 0), xev = xeu, xep = xeu;
        float4 yeu = xeu, yev = xeu, yep = xeu;
        if (isedge) {
            xeu = scale4(ld4(X + c + eoff), s);
            xev = scale4(ld4(X + c + CSTR + eoff), s);
            xep = ld4(X + c + 2 * CSTR + eoff);
            yeu = scale4(ld4(Y + c + eoff), s);
            yev = scale4(ld4(Y + c + CSTR + eoff), s);
            yep = ld4(Y + c + 2 * CSTR + eoff);
        }
        // j-group boundary scalars at plane b
        float xuL = 0, xvL = 0, xpL = 0, yuL = 0, yvL = 0, ypL = 0;
        float xuR = 0, xvR = 0, xpR = 0, yuR = 0, yvR = 0, ypR = 0;
        if (jl == 0) {
            xuL = X[c + offL] * s; xvL = X[c + CSTR + offL] * s;
            xpL = X[c + 2 * CSTR + offL];
            yuL = Y[c + offL] * s; yvL = Y[c + CSTR + offL] * s;
            ypL = Y[c + 2 * CSTR + offL];
        }
        if (jl == 7) {
            xuR = X[c + offR] * s; xvR = X[c + CSTR + offR] * s;
            xpR = X[c + 2 * CSTR + offR];
            yuR = Y[c + offR] * s; yvR = Y[c + CSTR + offR] * s;
            ypR = Y[c + 2 * CSTR + offR];
        }

        float r0x[4], r1x[4], r2x[4], r0y[4], r1y[4], r2y[4];
        resid(il, jl, xum, xuc, xun, xvm, xvc, xvn, xpc,
              xeu, xev, xep, xuL, xvL, xpL, xuR, xvR, xpR, sdx,
              r0x, r1x, r2x);
        resid(il, jl, yum, yuc, yun, yvm, yvc, yvn, ypc,
              yeu, yev, yep, yuL, yvL, ypL, yuR, yvR, ypR, sdx,
              r0y, r1y, r2y);

        #pragma unroll
        for (int k = 0; k < 4; ++k) {
            float e0 = r0y[k] - r0x[k];
            float e1 = r1y[k] - r1x[k];
            float e2 = r2y[k] - r2x[k];
            const bool dead = (!vrow) || (k == 0 && j0 == 0)
                                      || (k == 3 && j0 == 508);
            if (dead) { e0 = 0.0f; e1 = 0.0f; e2 = 0.0f; }
            s0 += e0 * e0; s1 += e1 * e1; s2 += e2 * e2;
        }

        // rotate chains
        xum = xuc; xuc = xun; xun = xun2;
        xvm = xvc; xvc = xvn; xvn = xvn2;
        yum = yuc; yuc = yun; yun = yun2;
        yvm = yvc; yvc = yvn; yvn = yvn2;
        c += BSTR;
    }

    // reduction: f32 wave shuffle -> LDS -> f64 atomic per block
    for (int o = 32; o > 0; o >>= 1) {
        s0 += __shfl_down(s0, o);
        s1 += __shfl_down(s1, o);
        s2 += __shfl_down(s2, o);
    }
    __shared__ float sm[3][4];
    if (lane == 0) { sm[0][w] = s0; sm[1][w] = s1; sm[2][w] = s2; }
    __syncthreads();
    if (tid == 0) {
        atomicAdd(&acc[0], (double)sm[0][0] + (double)sm[0][1]
                         + (double)sm[0][2] + (double)sm[0][3]);
        atomicAdd(&acc[1], (double)sm[1][0] + (double)sm[1][1]
                         + (double)sm[1][2] + (double)sm[1][3]);
        atomicAdd(&acc[2], (double)sm[2][0] + (double)sm[2][1]
                         + (double)sm[2][2] + (double)sm[2][3]);
    }
}

__global__ void ns_finalize_kernel(const double* __restrict__ acc,
                                   float* __restrict__ out)
{
    if (threadIdx.x == 0) {
        const double N = 62.0 * 510.0 * 510.0;
        out[0] = (float)(1.0e-3 * (acc[0] + acc[1] + acc[2]) / N);
    }
}

extern "C" void kernel_launch(void* const* d_in, const int* in_sizes, int n_in,
                              void* d_out, int out_size, void* d_ws, size_t ws_size,
                              hipStream_t stream) {
    const float* X    = (const float*)d_in[0];
    const float* Y    = (const float*)d_in[1];
    const float* stdp = (const float*)d_in[2];
    float* out  = (float*)d_out;
    double* acc = (double*)d_ws;

    hipMemsetAsync(acc, 0, 3 * sizeof(double), stream);

    dim3 block(256);
    dim3 grid(1024);  // 8 XCD groups x 16 i-tiles x 8 j-tiles; 4 blk/CU
    ns_loss_kernel<<<grid, block, 0, stream>>>(X, Y, stdp, acc);
    ns_finalize_kernel<<<1, 64, 0, stream>>>(acc, out);
}

// Round 17
// 136.550 us; speedup vs baseline: 1.1941x; 1.1941x over previous
//
#include <hip/hip_runtime.h>

// Navier-Stokes physics-informed loss (f32 in, scalar f32 out).
// x,y: (64,3,512,512). Interior: b in [1,62], i,j in [1,510].
// r0 = |dudx + dvdy| ; r1 = |dudt + u*dudx + v*dudy + dpdx - MU*lap u| ;
// r2 = |dvdt + u*dvdx + v*dvdy + dpdy - MU*lap v| ; dudt=(u[b+1]-u[b-1])*32
//
// Best = R14 (wall 124us): b-march, register-staged LDS centers, prefetch,
// raw barriers. Residual cost: 2 barriers x 16 iters at 2 blocks/CU + the
// same-iter LDS write->barrier->read chain.
// R17: DOUBLE-BUFFERED slab -> ONE barrier/iter. Iter k: compute plane k
// from buf[k&1]; stage plane k+1 (carried chain regs, no extra loads) into
// buf[k&1^1]; lgkmcnt(0)+s_barrier once. Staged data now loaded 2 iters
// before consumption. 256 thr = 4 rows x 64 f4-cols; LDS 48KiB -> 3
// blocks/CU (3-way barrier cover). Edge rows + j-boundary scalars loaded
// same-iter (L2-warm; drops R15's +12-reg carries).

constexpr int Wd   = 512;
constexpr int CSTR = 512 * 512;
constexpr int BSTR = 3 * 512 * 512;

__device__ __forceinline__ float4 ld4(const float* p) {
    return *reinterpret_cast<const float4*>(p);
}
__device__ __forceinline__ float4 scale4(float4 a, float s) {
    return make_float4(a.x * s, a.y * s, a.z * s, a.w * s);
}

// Residuals for one tensor at plane k.
// L: this tensor's current slab [field u,v,p][row 0..3][256] (u,v scaled; p raw)
// eu,ev (scaled), ep (raw): band-edge neighbor row (io 0 -> i-1, io 3 -> i+1).
// um,uc,un / vm,vc,vn: scaled b-chain. pc: raw p center row.
// uL..pR: j-boundary scalars for lanes jt 0/63 (u,v scaled; p raw).
__device__ __forceinline__ void plane_resid(
    const float (&L)[3][4][256],
    int io, int jt, int jl,
    float4 eu, float4 ev, float4 ep,
    float4 um, float4 uc, float4 un,
    float4 vm, float4 vc, float4 vn,
    float4 pc,
    float uL, float vL, float pL,
    float uR, float vR, float pR,
    float sdx,
    float r0[4], float r1[4], float r2[4])
{
    float4 uxm, vxm, pxm, uxp, vxp, pxp;
    if (io == 0) { uxm = eu; vxm = ev; pxm = ep; }
    else {
        uxm = ld4(&L[0][io - 1][jl]);
        vxm = ld4(&L[1][io - 1][jl]);
        pxm = ld4(&L[2][io - 1][jl]);
    }
    if (io == 3) { uxp = eu; vxp = ev; pxp = ep; }
    else {
        uxp = ld4(&L[0][io + 1][jl]);
        vxp = ld4(&L[1][io + 1][jl]);
        pxp = ld4(&L[2][io + 1][jl]);
    }

    // j+-1 via lane+-1 shfl on carried center regs; boundary lanes use scalars.
    float u_l = __shfl_up(uc.w, 1);
    float v_l = __shfl_up(vc.w, 1);
    float p_l = __shfl_up(pc.w, 1);
    float u_r = __shfl_down(uc.x, 1);
    float v_r = __shfl_down(vc.x, 1);
    float p_r = __shfl_down(pc.x, 1);
    if (jt == 0)  { u_l = uL; v_l = vL; p_l = pL; }
    if (jt == 63) { u_r = uR; v_r = vR; p_r = pR; }

    const float ucA[4] = {uc.x, uc.y, uc.z, uc.w};
    const float vcA[4] = {vc.x, vc.y, vc.z, vc.w};
    const float umA[4] = {um.x, um.y, um.z, um.w};
    const float vmA[4] = {vm.x, vm.y, vm.z, vm.w};
    const float unA[4] = {un.x, un.y, un.z, un.w};
    const float vnA[4] = {vn.x, vn.y, vn.z, vn.w};
    const float ul[4]  = {u_l, uc.x, uc.y, uc.z};
    const float ur[4]  = {uc.y, uc.z, uc.w, u_r};
    const float vl[4]  = {v_l, vc.x, vc.y, vc.z};
    const float vr[4]  = {vc.y, vc.z, vc.w, v_r};
    const float pl[4]  = {p_l, pc.x, pc.y, pc.z};
    const float pr[4]  = {pc.y, pc.z, pc.w, p_r};
    const float uxpA[4] = {uxp.x, uxp.y, uxp.z, uxp.w};
    const float uxmA[4] = {uxm.x, uxm.y, uxm.z, uxm.w};
    const float vxpA[4] = {vxp.x, vxp.y, vxp.z, vxp.w};
    const float vxmA[4] = {vxm.x, vxm.y, vxm.z, vxm.w};
    const float pxpA[4] = {pxp.x, pxp.y, pxp.z, pxp.w};
    const float pxmA[4] = {pxm.x, pxm.y, pxm.z, pxm.w};

    #pragma unroll
    for (int k = 0; k < 4; ++k) {
        const float dudx = (uxpA[k] - uxmA[k]) * 127.5f;   // scaled inputs
        const float dvdx = (vxpA[k] - vxmA[k]) * 127.5f;
        const float dpdx = (pxpA[k] - pxmA[k]) * sdx;      // raw p
        const float dudy = (ur[k] - ul[k]) * 127.5f;
        const float dvdy = (vr[k] - vl[k]) * 127.5f;
        const float dpdy = (pr[k] - pl[k]) * sdx;
        const float lapu = (uxpA[k] + uxmA[k] + ur[k] + ul[k]) * 0.65025f
                         - 2.601f * ucA[k];
        const float lapv = (vxpA[k] + vxmA[k] + vr[k] + vl[k]) * 0.65025f
                         - 2.601f * vcA[k];
        r0[k] = fabsf(dudx + dvdy);
        r1[k] = fabsf((unA[k] - umA[k]) * 32.0f + ucA[k] * dudx + vcA[k] * dudy
                      + dpdx - lapu);
        r2[k] = fabsf((vnA[k] - vmA[k]) * 32.0f + ucA[k] * dvdx + vcA[k] * dvdy
                      + dpdy - lapv);
    }
}

__global__ __launch_bounds__(256)
void ns_loss_kernel(const float* __restrict__ X, const float* __restrict__ Y,
                    const float* __restrict__ stdp, double* __restrict__ acc)
{
    __shared__ float lds[2][2][3][4][256];   // [buf][tensor][field][row][col] 48KiB
    __shared__ float smr[3][4];

    const float s   = *stdp;
    const float sdx = s * 127.5f;

    // XCD mapping: grp = orig&7 -> (b-chunk z, j-half jh); band = orig>>3
    // (contiguous i-bands within each XCD's L2).
    const int orig = blockIdx.x;
    const int grp  = orig & 7;
    const int band = orig >> 3;            // 0..127
    const int z    = grp >> 1;             // 0..3
    const int jh   = grp & 1;              // 0..1

    const int tid = threadIdx.x;
    const int io  = tid >> 6;              // row in band (wave-uniform)
    const int jt  = tid & 63;              // f4-col in half-row
    const int jl  = jt << 2;               // 0..252
    const int j0g = (jh << 8) + jl;        // global float col
    const int irow = 1 + band * 4 + io;
    const int i    = min(irow, 511);
    const bool vrow = (irow <= 510);
    const int bs = 1 + 15 * z + (z == 3 ? 1 : 0);   // 1,16,31,47
    const int nsteps = (z < 2) ? 15 : 16;

    int c = bs * BSTR + i * Wd + j0g;
    const int eoff = (io == 0) ? -Wd : ((i < 511) ? Wd : 0);
    const bool isedge = (io == 0) || (io == 3);
    const int offL = (j0g == 0) ? 0 : -1;            // clamped; masked at k=0
    const int offR = (j0g == 508) ? 3 : 4;           // clamped; masked at k=3

    // ---- prologue: chains at plane bs ----
    float4 xum = scale4(ld4(X + c - BSTR), s);
    float4 xuc = scale4(ld4(X + c), s);
    float4 xun = scale4(ld4(X + c + BSTR), s);
    float4 xvm = scale4(ld4(X + c - BSTR + CSTR), s);
    float4 xvc = scale4(ld4(X + c + CSTR), s);
    float4 xvn = scale4(ld4(X + c + BSTR + CSTR), s);
    float4 xpc = ld4(X + c + 2 * CSTR);
    float4 xpn = ld4(X + c + 2 * CSTR + BSTR);
    float4 yum = scale4(ld4(Y + c - BSTR), s);
    float4 yuc = scale4(ld4(Y + c), s);
    float4 yun = scale4(ld4(Y + c + BSTR), s);
    float4 yvm = scale4(ld4(Y + c - BSTR + CSTR), s);
    float4 yvc = scale4(ld4(Y + c + CSTR), s);
    float4 yvn = scale4(ld4(Y + c + BSTR + CSTR), s);
    float4 ypc = ld4(Y + c + 2 * CSTR);
    float4 ypn = ld4(Y + c + 2 * CSTR + BSTR);

    // stage plane 0 into buf 0
    *(float4*)&lds[0][0][0][io][jl] = xuc;
    *(float4*)&lds[0][0][1][io][jl] = xvc;
    *(float4*)&lds[0][0][2][io][jl] = xpc;
    *(float4*)&lds[0][1][0][io][jl] = yuc;
    *(float4*)&lds[0][1][1][io][jl] = yvc;
    *(float4*)&lds[0][1][2][io][jl] = ypc;
    __syncthreads();

    float s0 = 0.0f, s1 = 0.0f, s2 = 0.0f;

    for (int k = 0; k < nsteps; ++k) {
        const int cur = k & 1;

        // ---- edge rows + j-boundary scalars for plane k (L2-warm) ----
        float4 xeu = make_float4(0, 0, 0, 0), xev = xeu, xep = xeu;
        float4 yeu = xeu, yev = xeu, yep = xeu;
        if (isedge) {
            xeu = scale4(ld4(X + c + eoff), s);
            xev = scale4(ld4(X + c + CSTR + eoff), s);
            xep = ld4(X + c + 2 * CSTR + eoff);
            yeu = scale4(ld4(Y + c + eoff), s);
            yev = scale4(ld4(Y + c + CSTR + eoff), s);
            yep = ld4(Y + c + 2 * CSTR + eoff);
        }
        float xuL = 0, xvL = 0, xpL = 0, yuL = 0, yvL = 0, ypL = 0;
        float xuR = 0, xvR = 0, xpR = 0, yuR = 0, yvR = 0, ypR = 0;
        if (jt == 0) {
            xuL = X[c + offL] * s; xvL = X[c + CSTR + offL] * s;
            xpL = X[c + 2 * CSTR + offL];
            yuL = Y[c + offL] * s; yvL = Y[c + CSTR + offL] * s;
            ypL = Y[c + 2 * CSTR + offL];
        }
        if (jt == 63) {
            xuR = X[c + offR] * s; xvR = X[c + CSTR + offR] * s;
            xpR = X[c + 2 * CSTR + offR];
            yuR = Y[c + offR] * s; yvR = Y[c + CSTR + offR] * s;
            ypR = Y[c + 2 * CSTR + offR];
        }

        // ---- compute plane k from buf[cur] + chains ----
        float r0x[4], r1x[4], r2x[4], r0y[4], r1y[4], r2y[4];
        plane_resid(lds[cur][0], io, jt, jl, xeu, xev, xep,
                    xum, xuc, xun, xvm, xvc, xvn, xpc,
                    xuL, xvL, xpL, xuR, xvR, xpR, sdx, r0x, r1x, r2x);
        plane_resid(lds[cur][1], io, jt, jl, yeu, yev, yep,
                    yum, yuc, yun, yvm, yvc, yvn, ypc,
                    yuL, yvL, ypL, yuR, yvR, ypR, sdx, r0y, r1y, r2y);

        #pragma unroll
        for (int kk = 0; kk < 4; ++kk) {
            float e0 = r0y[kk] - r0x[kk];
            float e1 = r1y[kk] - r1x[kk];
            float e2 = r2y[kk] - r2x[kk];
            const bool dead = (!vrow) || (kk == 0 && j0g == 0)
                                      || (kk == 3 && j0g == 508);
            if (dead) { e0 = 0.0f; e1 = 0.0f; e2 = 0.0f; }
            s0 += e0 * e0; s1 += e1 * e1; s2 += e2 * e2;
        }

        // ---- stage plane k+1 (chain regs) into buf[cur^1] ----
        *(float4*)&lds[cur ^ 1][0][0][io][jl] = xun;
        *(float4*)&lds[cur ^ 1][0][1][io][jl] = xvn;
        *(float4*)&lds[cur ^ 1][0][2][io][jl] = xpn;
        *(float4*)&lds[cur ^ 1][1][0][io][jl] = yun;
        *(float4*)&lds[cur ^ 1][1][1][io][jl] = yvn;
        *(float4*)&lds[cur ^ 1][1][2][io][jl] = ypn;

        // ---- chain prefetch: plane k+2 (clamped to k+1 on last iter) ----
        const int pfo = (k + 1 < nsteps) ? 2 * BSTR : BSTR;
        const float4 xu2 = scale4(ld4(X + c + pfo), s);
        const float4 xv2 = scale4(ld4(X + c + pfo + CSTR), s);
        const float4 xp2 = ld4(X + c + pfo + 2 * CSTR);
        const float4 yu2 = scale4(ld4(Y + c + pfo), s);
        const float4 yv2 = scale4(ld4(Y + c + pfo + CSTR), s);
        const float4 yp2 = ld4(Y + c + pfo + 2 * CSTR);

        // ---- rotate chains ----
        xum = xuc; xuc = xun; xun = xu2;
        xvm = xvc; xvc = xvn; xvn = xv2;
        xpc = xpn; xpn = xp2;
        yum = yuc; yuc = yun; yun = yu2;
        yvm = yvc; yvc = yvn; yvn = yv2;
        ypc = ypn; ypn = yp2;

        // ---- single barrier: ds_writes visible; global prefetch in flight ----
        asm volatile("s_waitcnt lgkmcnt(0)" ::: "memory");
        __builtin_amdgcn_s_barrier();
        c += BSTR;
    }

    // ---- reduction: f32 wave shuffle -> LDS -> f64 atomic ----
    for (int o = 32; o > 0; o >>= 1) {
        s0 += __shfl_down(s0, o);
        s1 += __shfl_down(s1, o);
        s2 += __shfl_down(s2, o);
    }
    const int wid = tid >> 6;
    if (jt == 0) { smr[0][wid] = s0; smr[1][wid] = s1; smr[2][wid] = s2; }
    __syncthreads();
    if (tid == 0) {
        atomicAdd(&acc[0], (double)smr[0][0] + (double)smr[0][1]
                         + (double)smr[0][2] + (double)smr[0][3]);
        atomicAdd(&acc[1], (double)smr[1][0] + (double)smr[1][1]
                         + (double)smr[1][2] + (double)smr[1][3]);
        atomicAdd(&acc[2], (double)smr[2][0] + (double)smr[2][1]
                         + (double)smr[2][2] + (double)smr[2][3]);
    }
}

__global__ void ns_finalize_kernel(const double* __restrict__ acc,
                                   float* __restrict__ out)
{
    if (threadIdx.x == 0) {
        const double N = 62.0 * 510.0 * 510.0;
        out[0] = (float)(1.0e-3 * (acc[0] + acc[1] + acc[2]) / N);
    }
}

extern "C" void kernel_launch(void* const* d_in, const int* in_sizes, int n_in,
                              void* d_out, int out_size, void* d_ws, size_t ws_size,
                              hipStream_t stream) {
    const float* X    = (const float*)d_in[0];
    const float* Y    = (const float*)d_in[1];
    const float* stdp = (const float*)d_in[2];
    float* out  = (float*)d_out;
    double* acc = (double*)d_ws;

    hipMemsetAsync(acc, 0, 3 * sizeof(double), stream);

    dim3 block(256);
    dim3 grid(1024);  // 8 XCD groups (z,jh) x 128 bands; 3 blocks/CU
    ns_loss_kernel<<<grid, block, 0, stream>>>(X, Y, stdp, acc);
    ns_finalize_kernel<<<1, 64, 0, stream>>>(acc, out);
}